// Round 1
// baseline (947.191 us; speedup 1.0000x reference)
//
#include <hip/hip_runtime.h>

// NetEdge GNN round 7: channel-split gather (k_gchunk) replaces fused k_gfuse.
// zrel gather working set (12.8 MB) > per-XCD L2 (4 MB) made the gather
// L3-latency-bound (VALUBusy 28%, HBM 16%, occ 33%). Split 64 channels into
// 4 chunks of 16 (3.2 MB slice, L2-resident) and pin chunk = blockIdx&3 so
// the round-robin block->XCD mapping (%8) gives each XCD a single slice.
// W2-MLP un-fused into k_mlp2 (hrel round-trips through ws, aliasing xpad).
// Build (two-level MSD binning), ea_gather, mlp1v, pool, final unchanged
// (mlp1v grid 512 -> 768: 48KB LDS allows 3 blocks/CU).

namespace {
constexpr int N  = 50000;    // nodes
constexpr int E  = 1600000;  // edges
constexpr int G  = 256;      // graphs
constexpr int EC = 32;       // edge channels
constexpr int H  = 64;       // hidden / node channels
constexpr int D  = 96;       // concat dim (64 + 32)
constexpr int OUTC = 10;     // classes
constexpr int NB = (N + 255) / 256;   // 196 coarse buckets (node >> 8)
constexpr int CHUNK = 4096;           // edges per pass-1 block
}

// ---- pass 1a: coarse histograms ----
__global__ __launch_bounds__(256) void k_p1hist(const int* __restrict__ row,
                                                const int* __restrict__ col,
                                                int* __restrict__ cntR,
                                                int* __restrict__ cntC) {
    __shared__ int hR[NB], hC[NB];
    for (int i = threadIdx.x; i < NB; i += 256) { hR[i] = 0; hC[i] = 0; }
    __syncthreads();
    int base = blockIdx.x * CHUNK;
    int end = min(base + CHUNK, E);
    for (int e = base + threadIdx.x; e < end; e += 256) {
        atomicAdd(&hR[row[e] >> 8], 1);
        atomicAdd(&hC[col[e] >> 8], 1);
    }
    __syncthreads();
    for (int i = threadIdx.x; i < NB; i += 256) {
        if (hR[i]) atomicAdd(&cntR[i], hR[i]);
        if (hC[i]) atomicAdd(&cntC[i], hC[i]);
    }
}

// ---- pass 1b: scan bucket counts -> bases + cursors; off[N]=E ----
__global__ __launch_bounds__(256) void k_bscan(const int* __restrict__ cntR,
                                               const int* __restrict__ cntC,
                                               int* __restrict__ baseR, int* __restrict__ baseC,
                                               int* __restrict__ curR,  int* __restrict__ curC,
                                               int* __restrict__ offR,  int* __restrict__ offC) {
    __shared__ int sR[256], sC[256];
    int t = threadIdx.x;
    sR[t] = (t < NB) ? cntR[t] : 0;
    sC[t] = (t < NB) ? cntC[t] : 0;
    __syncthreads();
    for (int d = 1; d < 256; d <<= 1) {
        int vR = sR[t], vC = sC[t];
        int uR = (t >= d) ? sR[t - d] : 0;
        int uC = (t >= d) ? sC[t - d] : 0;
        __syncthreads();
        sR[t] = vR + uR; sC[t] = vC + uC;
        __syncthreads();
    }
    if (t < NB) {
        int bR = (t == 0) ? 0 : sR[t - 1];
        int bC = (t == 0) ? 0 : sC[t - 1];
        baseR[t] = bR; curR[t] = bR;
        baseC[t] = bC; curC[t] = bC;
    }
    if (t == 0) { offR[N] = E; offC[N] = E; }
}

// ---- pass 1c: coarse scatter of packed (key<<32|val) ----
__global__ __launch_bounds__(256) void k_p1scat(const int* __restrict__ row,
                                                const int* __restrict__ col,
                                                int* __restrict__ curR, int* __restrict__ curC,
                                                unsigned long long* __restrict__ kvR,
                                                unsigned long long* __restrict__ kvC) {
    __shared__ int hR[NB], hC[NB];
    __shared__ int cR[NB], cC[NB];
    for (int i = threadIdx.x; i < NB; i += 256) { hR[i] = 0; hC[i] = 0; }
    __syncthreads();
    int base = blockIdx.x * CHUNK;
    int end = min(base + CHUNK, E);
    for (int e = base + threadIdx.x; e < end; e += 256) {
        atomicAdd(&hR[row[e] >> 8], 1);
        atomicAdd(&hC[col[e] >> 8], 1);
    }
    __syncthreads();
    for (int i = threadIdx.x; i < NB; i += 256) {
        cR[i] = hR[i] ? atomicAdd(&curR[i], hR[i]) : 0;
        cC[i] = hC[i] ? atomicAdd(&curC[i], hC[i]) : 0;
    }
    __syncthreads();
    for (int e = base + threadIdx.x; e < end; e += 256) {
        int r = row[e], c = col[e];
        int pR = atomicAdd(&cR[r >> 8], 1);
        kvR[pR] = ((unsigned long long)(unsigned)r << 32) | (unsigned)e;
        int pC = atomicAdd(&cC[c >> 8], 1);
        kvC[pC] = ((unsigned long long)(unsigned)c << 32) | (unsigned)r;
    }
}

// ---- pass 2: per-bucket fine bin ----
__global__ __launch_bounds__(256) void k_p2(const unsigned long long* __restrict__ kvR,
                                            const unsigned long long* __restrict__ kvC,
                                            const int* __restrict__ baseR, const int* __restrict__ baseC,
                                            const int* __restrict__ cntR,  const int* __restrict__ cntC,
                                            int* __restrict__ offR, int* __restrict__ offC,
                                            int* __restrict__ eid, int* __restrict__ srcrow) {
    bool isC = blockIdx.x >= NB;
    int b = isC ? blockIdx.x - NB : blockIdx.x;
    const unsigned long long* kv = isC ? kvC : kvR;
    int sbase = isC ? baseC[b] : baseR[b];
    int scnt  = isC ? cntC[b]  : cntR[b];
    int* off  = isC ? offC : offR;
    int* outv = isC ? srcrow : eid;

    __shared__ int hist[256], s[256], cur[256];
    int t = threadIdx.x;
    hist[t] = 0;
    __syncthreads();
    for (int i = sbase + t; i < sbase + scnt; i += 256) {
        atomicAdd(&hist[(int)(kv[i] >> 32) & 255], 1);
    }
    __syncthreads();
    s[t] = hist[t];
    __syncthreads();
    for (int d = 1; d < 256; d <<= 1) {
        int v = s[t];
        int u = (t >= d) ? s[t - d] : 0;
        __syncthreads();
        s[t] = v + u;
        __syncthreads();
    }
    int excl = (t == 0) ? 0 : s[t - 1];
    cur[t] = sbase + excl;
    int node = (b << 8) + t;
    if (node < N) off[node] = sbase + excl;
    __syncthreads();
    for (int i = sbase + t; i < sbase + scnt; i += 256) {
        unsigned long long p = kv[i];
        int lk = (int)(p >> 32) & 255;
        int pos = atomicAdd(&cur[lk], 1);
        outv[pos] = (int)(p & 0xffffffffu);
    }
}

// ---- ea[n] = sum of edge_attr over outgoing edges; float4, 8 edges/load ----
// wave per node: grp = lane>>3 (edge in group of 8), q = lane&7 (float4 chunk).
__global__ __launch_bounds__(256) void k_ea_gather(const float4* __restrict__ ea4_in,
                                                   const int* __restrict__ eid,
                                                   const int* __restrict__ offR,
                                                   float4* __restrict__ ea_out) {
    int n = blockIdx.x * 4 + (threadIdx.x >> 6);
    int lane = threadIdx.x & 63;
    if (n >= N) return;
    int grp = lane >> 3;
    int q   = lane & 7;
    int b = offR[n], e_end = offR[n + 1];
    float4 acc = make_float4(0.f, 0.f, 0.f, 0.f);
    for (int i0 = b; i0 < e_end; i0 += 32) {
        int lim = e_end - i0;
        int ev = eid[min(i0 + lane, e_end - 1)];
        if (lim >= 32) {
            float4 v[4];
            #pragma unroll
            for (int s = 0; s < 4; ++s) {
                int e = __shfl(ev, s * 8 + grp);
                v[s] = ea4_in[(size_t)e * 8 + q];
            }
            #pragma unroll
            for (int s = 0; s < 4; ++s) {
                acc.x += v[s].x; acc.y += v[s].y; acc.z += v[s].z; acc.w += v[s].w;
            }
        } else {
            int steps = (lim + 7) >> 3;
            for (int s = 0; s < steps; ++s) {
                int eidx = s * 8 + grp;
                int e = __shfl(ev, eidx);
                float4 v = ea4_in[(size_t)e * 8 + q];
                if (eidx < lim) {
                    acc.x += v.x; acc.y += v.y; acc.z += v.z; acc.w += v.w;
                }
            }
        }
    }
    // reduce across the 8 edge-groups (lanes q, q+8, ..., q+56)
    #pragma unroll
    for (int m = 8; m <= 32; m <<= 1) {
        acc.x += __shfl_xor(acc.x, m);
        acc.y += __shfl_xor(acc.y, m);
        acc.z += __shfl_xor(acc.z, m);
        acc.w += __shfl_xor(acc.w, m);
    }
    if (lane < 8) ea_out[(size_t)n * 8 + q] = acc;
}

// ---- zrel = [head‖ea] @ relW1 (no bias); hroot = relu([head‖ea] @ rootW1 + b) ----
__global__ __launch_bounds__(256) void k_mlp1v(const float* __restrict__ head,
                        const float* __restrict__ ea,
                        const float* __restrict__ relW1,
                        const float* __restrict__ rootW1, const float* __restrict__ rootb1,
                        float* __restrict__ zrel, float* __restrict__ hroot) {
    __shared__ float sWz[D * H];
    __shared__ float sWh[D * H];
    for (int i = threadIdx.x; i < D * H; i += 256) {
        sWz[i] = relW1[i];
        sWh[i] = rootW1[i];
    }
    __syncthreads();
    int lane = threadIdx.x & 63;
    int wid  = threadIdx.x >> 6;
    int nwaves = gridDim.x * 4;
    float bo = rootb1[lane];
    for (int n = blockIdx.x * 4 + wid; n < N; n += nwaves) {
        float h0 = head[(size_t)n * H + lane];
        float h1 = (lane < EC) ? ea[(size_t)n * EC + lane] : 0.f;
        float accz = 0.f, acch = bo;
        #pragma unroll 8
        for (int k = 0; k < H; ++k) {
            float v = __shfl(h0, k);
            accz += v * sWz[k * H + lane];
            acch += v * sWh[k * H + lane];
        }
        #pragma unroll 8
        for (int k = 0; k < EC; ++k) {
            float v = __shfl(h1, k);
            accz += v * sWz[(H + k) * H + lane];
            acch += v * sWh[(H + k) * H + lane];
        }
        zrel[(size_t)n * H + lane]  = accz;
        hroot[(size_t)n * H + lane] = fmaxf(acch, 0.f);
    }
}

// ---- channel-split gather: chunk = blockIdx&3 (16 channels = 3.2 MB slice,
//      L2-resident per XCD pair via blockIdx%8 round-robin); per edge 64 B,
//      16 edges per wave-load (grp=lane>>2, q=lane&3); no LDS -> 8 blocks/CU.
//      hrel[n][c16] = relu(gather-sum + b1[c16]) ----
__global__ __launch_bounds__(256) void k_gchunk(const float4* __restrict__ z4,
                        const int* __restrict__ srcrow,
                        const int* __restrict__ offC,
                        const float4* __restrict__ relb1_4,
                        float4* __restrict__ hrel4) {
    int c  = blockIdx.x & 3;        // channel chunk (16 floats)
    int nb = blockIdx.x >> 2;       // node-block within chunk
    int lane = threadIdx.x & 63;
    int wid  = threadIdx.x >> 6;
    int grp = lane >> 2;            // 16 edge subgroups
    int q   = lane & 3;             // float4 within the chunk
    int c4 = c * 4;                 // float4 offset of this chunk in the row
    int nwaves = (gridDim.x >> 2) * 4;   // waves per chunk
    float4 b1 = relb1_4[c4 + q];
    for (int n = nb * 4 + wid; n < N; n += nwaves) {
        int b = offC[n], e_end = offC[n + 1];
        float4 acc = make_float4(0.f, 0.f, 0.f, 0.f);
        for (int i0 = b; i0 < e_end; i0 += 64) {
            int lim = e_end - i0;
            int rv = srcrow[min(i0 + lane, e_end - 1)];
            if (lim >= 64) {
                float4 v[4];
                #pragma unroll
                for (int s = 0; s < 4; ++s) {
                    int src = __shfl(rv, s * 16 + grp);
                    v[s] = z4[(size_t)src * 16 + c4 + q];
                }
                #pragma unroll
                for (int s = 0; s < 4; ++s) {
                    acc.x += v[s].x; acc.y += v[s].y; acc.z += v[s].z; acc.w += v[s].w;
                }
            } else {
                int steps = (lim + 15) >> 4;
                for (int s = 0; s < steps; ++s) {
                    int eidx = s * 16 + grp;
                    int src = __shfl(rv, eidx);
                    float4 v = z4[(size_t)src * 16 + c4 + q];
                    if (eidx < lim) {
                        acc.x += v.x; acc.y += v.y; acc.z += v.z; acc.w += v.w;
                    }
                }
            }
        }
        // reduce across the 16 edge-groups (lanes q, q+4, ..., q+60)
        #pragma unroll
        for (int m = 4; m <= 32; m <<= 1) {
            acc.x += __shfl_xor(acc.x, m);
            acc.y += __shfl_xor(acc.y, m);
            acc.z += __shfl_xor(acc.z, m);
            acc.w += __shfl_xor(acc.w, m);
        }
        if (lane < 4) {
            float4 h;
            h.x = fmaxf(acc.x + b1.x, 0.f);
            h.y = fmaxf(acc.y + b1.y, 0.f);
            h.z = fmaxf(acc.z + b1.z, 0.f);
            h.w = fmaxf(acc.w + b1.w, 0.f);
            hrel4[(size_t)n * 16 + c4 + q] = h;
        }
    }
}

// ---- xout = relu(hrel@relW2 + hroot@rootW2 + relb2 + rootb2) ----
__global__ __launch_bounds__(256) void k_mlp2(const float* __restrict__ hrel,
                        const float* __restrict__ hroot,
                        const float* __restrict__ relW2, const float* __restrict__ relb2,
                        const float* __restrict__ rootW2, const float* __restrict__ rootb2,
                        float* __restrict__ xout) {
    __shared__ float sWr[H * H];
    __shared__ float sWo[H * H];
    for (int i = threadIdx.x; i < H * H; i += 256) {
        sWr[i] = relW2[i];
        sWo[i] = rootW2[i];
    }
    __syncthreads();
    int lane = threadIdx.x & 63;
    int wid  = threadIdx.x >> 6;
    int nwaves = gridDim.x * 4;
    float b2 = relb2[lane] + rootb2[lane];
    for (int n = blockIdx.x * 4 + wid; n < N; n += nwaves) {
        float h  = hrel[(size_t)n * H + lane];
        float ho = hroot[(size_t)n * H + lane];
        float o = b2;
        #pragma unroll 8
        for (int k = 0; k < H; ++k) {
            o += __shfl(h, k) * sWr[k * H + lane] + __shfl(ho, k) * sWo[k * H + lane];
        }
        xout[(size_t)n * H + lane] = fmaxf(o, 0.f);
    }
}

// ---- pooled[batch[n]] += x[n], 16-node register pre-reduce (batch sorted) ----
__global__ __launch_bounds__(256) void k_pool(const float* __restrict__ x,
                                              const int* __restrict__ batch,
                                              float* __restrict__ pooled) {
    int c = threadIdx.x & 63;
    int grp = blockIdx.x * 4 + (threadIdx.x >> 6);
    int n0 = grp * 16;
    if (n0 >= N) return;
    int nend = min(n0 + 16, N);
    int curb = batch[n0];
    float acc = 0.f;
    for (int n = n0; n < nend; ++n) {
        int b = batch[n];
        if (b != curb) {
            atomicAdd(&pooled[curb * H + c], acc);
            acc = 0.f;
            curb = b;
        }
        acc += x[(size_t)n * H + c];
    }
    atomicAdd(&pooled[curb * H + c], acc);
}

// ---- out = relu(pooled @ finW1 + finb1) @ finW2 + finb2 ----
__global__ void k_final(const float* __restrict__ pooled,
                        const float* __restrict__ W1, const float* __restrict__ b1,
                        const float* __restrict__ W2, const float* __restrict__ b2,
                        float* __restrict__ out) {
    __shared__ float h[H];
    int g = blockIdx.x;
    int j = threadIdx.x;
    const float* p = pooled + (size_t)g * H;
    float acc = b1[j];
    #pragma unroll 8
    for (int k = 0; k < H; ++k) acc += p[k] * W1[k * H + j];
    h[j] = fmaxf(acc, 0.f);
    __syncthreads();
    if (j < OUTC) {
        float o = b2[j];
        #pragma unroll 8
        for (int k = 0; k < H; ++k) o += h[k] * W2[k * OUTC + j];
        out[(size_t)g * OUTC + j] = o;
    }
}

extern "C" void kernel_launch(void* const* d_in, const int* in_sizes, int n_in,
                              void* d_out, int out_size, void* d_ws, size_t ws_size,
                              hipStream_t stream) {
    const float* x         = (const float*)d_in[0];
    const float* edge_attr = (const float*)d_in[1];
    const float* P[16];
    for (int i = 0; i < 16; ++i) P[i] = (const float*)d_in[2 + i];
    const float* finW1 = (const float*)d_in[18];
    const float* finb1 = (const float*)d_in[19];
    const float* finW2 = (const float*)d_in[20];
    const float* finb2 = (const float*)d_in[21];
    const int* row   = (const int*)d_in[22];
    const int* col   = row + E;
    const int* batch = (const int*)d_in[23];
    float* out = (float*)d_out;
    (void)ws_size; (void)n_in; (void)in_sizes; (void)out_size;

    // ---- workspace ----
    float* fw = (float*)d_ws;
    float* zrel   = fw;  fw += (size_t)N * H;   // aliased by kvR during build
    float* hroot  = fw;  fw += (size_t)N * H;   // aliased by kvR during build
    float* x1     = fw;  fw += (size_t)N * H;   // aliased by kvC during build
    float* hrel   = fw;  fw += (size_t)N * H;   // aliased by kvC during build (was xpad)
    float* ea     = fw;  fw += (size_t)N * EC;
    float* pooled = fw;  fw += (size_t)G * H;
    int* iw = (int*)fw;
    int* cntR   = iw;  iw += NB;
    int* cntC   = iw;  iw += NB;
    int* baseR  = iw;  iw += NB;
    int* baseC  = iw;  iw += NB;
    int* curR   = iw;  iw += NB;
    int* curC   = iw;  iw += NB;
    int* offR   = iw;  iw += N + 1;
    int* offC   = iw;  iw += N + 1;
    int* eid    = iw;  iw += E;
    int* srcrow = iw;  iw += E;
    // kv arrays (E x 8B each) alias node float arrays (build-only lifetime)
    unsigned long long* kvR = (unsigned long long*)zrel;   // covers zrel+hroot
    unsigned long long* kvC = (unsigned long long*)x1;     // covers x1+hrel

    // ---- build CSR/CSC ----
    hipMemsetAsync(cntR, 0, 2 * (size_t)NB * sizeof(int), stream);
    hipMemsetAsync(pooled, 0, (size_t)G * H * sizeof(float), stream);
    int p1grid = (E + CHUNK - 1) / CHUNK;
    k_p1hist<<<p1grid, 256, 0, stream>>>(row, col, cntR, cntC);
    k_bscan<<<1, 256, 0, stream>>>(cntR, cntC, baseR, baseC, curR, curC, offR, offC);
    k_p1scat<<<p1grid, 256, 0, stream>>>(row, col, curR, curC, kvR, kvC);
    k_p2<<<2 * NB, 256, 0, stream>>>(kvR, kvC, baseR, baseC, cntR, cntC,
                                     offR, offC, eid, srcrow);

    // ---- shared edge aggregation ----
    k_ea_gather<<<(N + 3) / 4, 256, 0, stream>>>((const float4*)edge_attr, eid, offR,
                                                 (float4*)ea);

    // ---- layer 1 ----
    k_mlp1v<<<768, 256, 0, stream>>>(x, ea, P[0], P[4], P[5], zrel, hroot);
    k_gchunk<<<4096, 256, 0, stream>>>((const float4*)zrel, srcrow, offC,
                                       (const float4*)P[1], (float4*)hrel);
    k_mlp2<<<1024, 256, 0, stream>>>(hrel, hroot, P[2], P[3], P[6], P[7], x1);

    // ---- layer 2 ----
    k_mlp1v<<<768, 256, 0, stream>>>(x1, ea, P[8], P[12], P[13], zrel, hroot);
    k_gchunk<<<4096, 256, 0, stream>>>((const float4*)zrel, srcrow, offC,
                                       (const float4*)P[9], (float4*)hrel);
    k_mlp2<<<1024, 256, 0, stream>>>(hrel, hroot, P[10], P[11], P[14], P[15], x1);

    // ---- pool + head ----
    k_pool<<<(N / 16 + 3) / 4, 256, 0, stream>>>(x1, batch, pooled);
    k_final<<<G, 64, 0, stream>>>(pooled, finW1, finb1, finW2, finb2, out);
}

// Round 2
// 656.997 us; speedup vs baseline: 1.4417x; 1.4417x over previous
//
#include <hip/hip_runtime.h>

// NetEdge GNN round 8: DS-pipe-bound MLPs replaced by register-tiled GEMMs.
// Post-mortem r6/r7: k_gfuse's 128us was LDS-pipe throughput (256 DS instr
// per node in the shuffle MLP tail: 64x(2 bpermute + 2 ds_read_b32) ~= 1660
// cyc/node x 195 nodes/CU = 135us -- matches measurement). Fix: per layer
//   k_mlp1g: [x||ea](Nx96) @ [Wz||Wh](96x128) -> zrel,hroot  (tiled GEMM)
//   k_gath : pure gather+bias+relu, no LDS, 8 loads always in flight
//   k_mlp2g: [hrel||hroot](Nx128) @ [Wr;Wo](128x64) -> x1    (tiled GEMM)
// Build (two-level MSD binning), ea_gather, pool, final unchanged.

namespace {
constexpr int N  = 50000;    // nodes
constexpr int E  = 1600000;  // edges
constexpr int G  = 256;      // graphs
constexpr int EC = 32;       // edge channels
constexpr int H  = 64;       // hidden / node channels
constexpr int OUTC = 10;     // classes
constexpr int NB = (N + 255) / 256;   // 196 coarse buckets (node >> 8)
constexpr int CHUNK = 4096;           // edges per pass-1 block
}

// ---- pass 1a: coarse histograms ----
__global__ __launch_bounds__(256) void k_p1hist(const int* __restrict__ row,
                                                const int* __restrict__ col,
                                                int* __restrict__ cntR,
                                                int* __restrict__ cntC) {
    __shared__ int hR[NB], hC[NB];
    for (int i = threadIdx.x; i < NB; i += 256) { hR[i] = 0; hC[i] = 0; }
    __syncthreads();
    int base = blockIdx.x * CHUNK;
    int end = min(base + CHUNK, E);
    for (int e = base + threadIdx.x; e < end; e += 256) {
        atomicAdd(&hR[row[e] >> 8], 1);
        atomicAdd(&hC[col[e] >> 8], 1);
    }
    __syncthreads();
    for (int i = threadIdx.x; i < NB; i += 256) {
        if (hR[i]) atomicAdd(&cntR[i], hR[i]);
        if (hC[i]) atomicAdd(&cntC[i], hC[i]);
    }
}

// ---- pass 1b: scan bucket counts -> bases + cursors; off[N]=E ----
__global__ __launch_bounds__(256) void k_bscan(const int* __restrict__ cntR,
                                               const int* __restrict__ cntC,
                                               int* __restrict__ baseR, int* __restrict__ baseC,
                                               int* __restrict__ curR,  int* __restrict__ curC,
                                               int* __restrict__ offR,  int* __restrict__ offC) {
    __shared__ int sR[256], sC[256];
    int t = threadIdx.x;
    sR[t] = (t < NB) ? cntR[t] : 0;
    sC[t] = (t < NB) ? cntC[t] : 0;
    __syncthreads();
    for (int d = 1; d < 256; d <<= 1) {
        int vR = sR[t], vC = sC[t];
        int uR = (t >= d) ? sR[t - d] : 0;
        int uC = (t >= d) ? sC[t - d] : 0;
        __syncthreads();
        sR[t] = vR + uR; sC[t] = vC + uC;
        __syncthreads();
    }
    if (t < NB) {
        int bR = (t == 0) ? 0 : sR[t - 1];
        int bC = (t == 0) ? 0 : sC[t - 1];
        baseR[t] = bR; curR[t] = bR;
        baseC[t] = bC; curC[t] = bC;
    }
    if (t == 0) { offR[N] = E; offC[N] = E; }
}

// ---- pass 1c: coarse scatter of packed (key<<32|val) ----
__global__ __launch_bounds__(256) void k_p1scat(const int* __restrict__ row,
                                                const int* __restrict__ col,
                                                int* __restrict__ curR, int* __restrict__ curC,
                                                unsigned long long* __restrict__ kvR,
                                                unsigned long long* __restrict__ kvC) {
    __shared__ int hR[NB], hC[NB];
    __shared__ int cR[NB], cC[NB];
    for (int i = threadIdx.x; i < NB; i += 256) { hR[i] = 0; hC[i] = 0; }
    __syncthreads();
    int base = blockIdx.x * CHUNK;
    int end = min(base + CHUNK, E);
    for (int e = base + threadIdx.x; e < end; e += 256) {
        atomicAdd(&hR[row[e] >> 8], 1);
        atomicAdd(&hC[col[e] >> 8], 1);
    }
    __syncthreads();
    for (int i = threadIdx.x; i < NB; i += 256) {
        cR[i] = hR[i] ? atomicAdd(&curR[i], hR[i]) : 0;
        cC[i] = hC[i] ? atomicAdd(&curC[i], hC[i]) : 0;
    }
    __syncthreads();
    for (int e = base + threadIdx.x; e < end; e += 256) {
        int r = row[e], c = col[e];
        int pR = atomicAdd(&cR[r >> 8], 1);
        kvR[pR] = ((unsigned long long)(unsigned)r << 32) | (unsigned)e;
        int pC = atomicAdd(&cC[c >> 8], 1);
        kvC[pC] = ((unsigned long long)(unsigned)c << 32) | (unsigned)r;
    }
}

// ---- pass 2: per-bucket fine bin ----
__global__ __launch_bounds__(256) void k_p2(const unsigned long long* __restrict__ kvR,
                                            const unsigned long long* __restrict__ kvC,
                                            const int* __restrict__ baseR, const int* __restrict__ baseC,
                                            const int* __restrict__ cntR,  const int* __restrict__ cntC,
                                            int* __restrict__ offR, int* __restrict__ offC,
                                            int* __restrict__ eid, int* __restrict__ srcrow) {
    bool isC = blockIdx.x >= NB;
    int b = isC ? blockIdx.x - NB : blockIdx.x;
    const unsigned long long* kv = isC ? kvC : kvR;
    int sbase = isC ? baseC[b] : baseR[b];
    int scnt  = isC ? cntC[b]  : cntR[b];
    int* off  = isC ? offC : offR;
    int* outv = isC ? srcrow : eid;

    __shared__ int hist[256], s[256], cur[256];
    int t = threadIdx.x;
    hist[t] = 0;
    __syncthreads();
    for (int i = sbase + t; i < sbase + scnt; i += 256) {
        atomicAdd(&hist[(int)(kv[i] >> 32) & 255], 1);
    }
    __syncthreads();
    s[t] = hist[t];
    __syncthreads();
    for (int d = 1; d < 256; d <<= 1) {
        int v = s[t];
        int u = (t >= d) ? s[t - d] : 0;
        __syncthreads();
        s[t] = v + u;
        __syncthreads();
    }
    int excl = (t == 0) ? 0 : s[t - 1];
    cur[t] = sbase + excl;
    int node = (b << 8) + t;
    if (node < N) off[node] = sbase + excl;
    __syncthreads();
    for (int i = sbase + t; i < sbase + scnt; i += 256) {
        unsigned long long p = kv[i];
        int lk = (int)(p >> 32) & 255;
        int pos = atomicAdd(&cur[lk], 1);
        outv[pos] = (int)(p & 0xffffffffu);
    }
}

// ---- ea[n] = sum of edge_attr over outgoing edges; float4, 8 edges/load ----
__global__ __launch_bounds__(256) void k_ea_gather(const float4* __restrict__ ea4_in,
                                                   const int* __restrict__ eid,
                                                   const int* __restrict__ offR,
                                                   float4* __restrict__ ea_out) {
    int n = blockIdx.x * 4 + (threadIdx.x >> 6);
    int lane = threadIdx.x & 63;
    if (n >= N) return;
    int grp = lane >> 3;
    int q   = lane & 7;
    int b = offR[n], e_end = offR[n + 1];
    float4 acc = make_float4(0.f, 0.f, 0.f, 0.f);
    for (int i0 = b; i0 < e_end; i0 += 32) {
        int lim = e_end - i0;
        int ev = eid[min(i0 + lane, e_end - 1)];
        float4 v[4];
        #pragma unroll
        for (int s = 0; s < 4; ++s) {
            int e = __shfl(ev, s * 8 + grp);
            v[s] = ea4_in[(size_t)e * 8 + q];
        }
        #pragma unroll
        for (int s = 0; s < 4; ++s) {
            if (s * 8 + grp < lim) {
                acc.x += v[s].x; acc.y += v[s].y; acc.z += v[s].z; acc.w += v[s].w;
            }
        }
    }
    #pragma unroll
    for (int m = 8; m <= 32; m <<= 1) {
        acc.x += __shfl_xor(acc.x, m);
        acc.y += __shfl_xor(acc.y, m);
        acc.z += __shfl_xor(acc.z, m);
        acc.w += __shfl_xor(acc.w, m);
    }
    if (lane < 8) ea_out[(size_t)n * 8 + q] = acc;
}

// ---- k_mlp1g: C[n,0:64]=zrel=[x||ea]@Wz, C[n,64:128]=relu([x||ea]@Wh+bh) ----
// 32-node block, 256 threads, thread tile 2 rows x 8 cols, LDS ~62 KB.
__global__ __launch_bounds__(256) void k_mlp1g(const float* __restrict__ x,
                        const float* __restrict__ ea,
                        const float* __restrict__ Wz, const float* __restrict__ Wh,
                        const float* __restrict__ bh,
                        float* __restrict__ zrel, float* __restrict__ hroot) {
    __shared__ float As[32][100];    // [node][k], 96 padded to 100
    __shared__ float Ws[96][128];    // [k][j]: j<64 -> Wz, j>=64 -> Wh
    int n0 = blockIdx.x * 32;
    int t = threadIdx.x;
    {   // stage x (cols 0..63)
        int c4 = (t & 15) * 4;
        int r0 = t >> 4;
        #pragma unroll
        for (int r = r0; r < 32; r += 16) {
            int n = min(n0 + r, N - 1);
            *(float4*)&As[r][c4] = *(const float4*)&x[(size_t)n * H + c4];
        }
        // stage ea (cols 64..95)
        int c2 = (t & 7) * 4;
        int r1 = t >> 3;             // 0..31
        int n = min(n0 + r1, N - 1);
        *(float4*)&As[r1][64 + c2] = *(const float4*)&ea[(size_t)n * EC + c2];
    }
    for (int i = t; i < 96 * 128; i += 256) {
        int k = i >> 7, j = i & 127;
        Ws[k][j] = (j < 64) ? Wz[k * 64 + j] : Wh[k * 64 + (j - 64)];
    }
    __syncthreads();
    int tr = t >> 4;                 // rows tr*2 .. tr*2+1
    int tc = t & 15;                 // cols tc*8 .. tc*8+7
    float acc[2][8];
    #pragma unroll
    for (int i = 0; i < 2; ++i)
        #pragma unroll
        for (int j = 0; j < 8; ++j) acc[i][j] = 0.f;
    #pragma unroll 2
    for (int k = 0; k < 96; k += 4) {
        float4 a0 = *(const float4*)&As[tr * 2][k];
        float4 a1 = *(const float4*)&As[tr * 2 + 1][k];
        #pragma unroll
        for (int kk = 0; kk < 4; ++kk) {
            float4 w0 = *(const float4*)&Ws[k + kk][tc * 8];
            float4 w1 = *(const float4*)&Ws[k + kk][tc * 8 + 4];
            float av0 = (kk == 0) ? a0.x : (kk == 1) ? a0.y : (kk == 2) ? a0.z : a0.w;
            float av1 = (kk == 0) ? a1.x : (kk == 1) ? a1.y : (kk == 2) ? a1.z : a1.w;
            acc[0][0] += av0 * w0.x; acc[0][1] += av0 * w0.y;
            acc[0][2] += av0 * w0.z; acc[0][3] += av0 * w0.w;
            acc[0][4] += av0 * w1.x; acc[0][5] += av0 * w1.y;
            acc[0][6] += av0 * w1.z; acc[0][7] += av0 * w1.w;
            acc[1][0] += av1 * w0.x; acc[1][1] += av1 * w0.y;
            acc[1][2] += av1 * w0.z; acc[1][3] += av1 * w0.w;
            acc[1][4] += av1 * w1.x; acc[1][5] += av1 * w1.y;
            acc[1][6] += av1 * w1.z; acc[1][7] += av1 * w1.w;
        }
    }
    if (tc < 8) {                    // zrel cols, no bias, no relu
        int jb = tc * 8;
        #pragma unroll
        for (int i = 0; i < 2; ++i) {
            int n = n0 + tr * 2 + i;
            if (n < N) {
                *(float4*)&zrel[(size_t)n * H + jb] =
                    make_float4(acc[i][0], acc[i][1], acc[i][2], acc[i][3]);
                *(float4*)&zrel[(size_t)n * H + jb + 4] =
                    make_float4(acc[i][4], acc[i][5], acc[i][6], acc[i][7]);
            }
        }
    } else {                         // hroot cols, +bias, relu
        int jb = (tc - 8) * 8;
        float4 b0 = *(const float4*)&bh[jb];
        float4 b1v = *(const float4*)&bh[jb + 4];
        #pragma unroll
        for (int i = 0; i < 2; ++i) {
            int n = n0 + tr * 2 + i;
            if (n < N) {
                *(float4*)&hroot[(size_t)n * H + jb] = make_float4(
                    fmaxf(acc[i][0] + b0.x, 0.f), fmaxf(acc[i][1] + b0.y, 0.f),
                    fmaxf(acc[i][2] + b0.z, 0.f), fmaxf(acc[i][3] + b0.w, 0.f));
                *(float4*)&hroot[(size_t)n * H + jb + 4] = make_float4(
                    fmaxf(acc[i][4] + b1v.x, 0.f), fmaxf(acc[i][5] + b1v.y, 0.f),
                    fmaxf(acc[i][6] + b1v.z, 0.f), fmaxf(acc[i][7] + b1v.w, 0.f));
            }
        }
    }
}

// ---- k_gath: hrel[n] = relu(sum_{e in CSC(n)} zrel[src(e)] + relb1) ----
// wave per node, no LDS (max occupancy), 8 loads always in flight.
__global__ __launch_bounds__(256) void k_gath(const float4* __restrict__ z4,
                        const int* __restrict__ srcrow,
                        const int* __restrict__ offC,
                        const float4* __restrict__ relb1_4,
                        float4* __restrict__ hrel4) {
    int n = blockIdx.x * 4 + (threadIdx.x >> 6);
    if (n >= N) return;
    int lane = threadIdx.x & 63;
    int grp = lane >> 4;   // edge subgroup 0..3
    int q   = lane & 15;   // float4 chunk of the 64-ch row
    int b = offC[n], e_end = offC[n + 1];
    float4 acc = make_float4(0.f, 0.f, 0.f, 0.f);
    for (int i0 = b; i0 < e_end; i0 += 32) {
        int lim = e_end - i0;
        int rv = srcrow[min(i0 + lane, e_end - 1)];
        float4 v[8];
        #pragma unroll
        for (int s = 0; s < 8; ++s) {
            int src = __shfl(rv, s * 4 + grp);
            v[s] = z4[(size_t)src * 16 + q];
        }
        #pragma unroll
        for (int s = 0; s < 8; ++s) {
            if (s * 4 + grp < lim) {
                acc.x += v[s].x; acc.y += v[s].y; acc.z += v[s].z; acc.w += v[s].w;
            }
        }
    }
    #pragma unroll
    for (int m = 16; m <= 32; m <<= 1) {
        acc.x += __shfl_xor(acc.x, m);
        acc.y += __shfl_xor(acc.y, m);
        acc.z += __shfl_xor(acc.z, m);
        acc.w += __shfl_xor(acc.w, m);
    }
    if (lane < 16) {
        float4 b1 = relb1_4[q];
        float4 h;
        h.x = fmaxf(acc.x + b1.x, 0.f);
        h.y = fmaxf(acc.y + b1.y, 0.f);
        h.z = fmaxf(acc.z + b1.z, 0.f);
        h.w = fmaxf(acc.w + b1.w, 0.f);
        hrel4[(size_t)n * 16 + q] = h;
    }
}

// ---- k_mlp2g: xout = relu([hrel||hroot](Nx128) @ [Wr;Wo](128x64) + br+bo) ----
// 32-node block, 256 threads, thread tile 2 rows x 4 cols, LDS ~49 KB.
__global__ __launch_bounds__(256) void k_mlp2g(const float* __restrict__ hrel,
                        const float* __restrict__ hroot,
                        const float* __restrict__ Wr, const float* __restrict__ Wo,
                        const float* __restrict__ br, const float* __restrict__ bo,
                        float* __restrict__ xout) {
    __shared__ float As[32][132];    // [node][k]: k<64 hrel, k>=64 hroot (pad 128->132)
    __shared__ float Ws[128][64];    // [k][j]: k<64 Wr, k>=64 Wo
    int n0 = blockIdx.x * 32;
    int t = threadIdx.x;
    {
        int c4 = (t & 15) * 4;
        int r0 = t >> 4;
        #pragma unroll
        for (int r = r0; r < 32; r += 16) {
            int n = min(n0 + r, N - 1);
            *(float4*)&As[r][c4]      = *(const float4*)&hrel [(size_t)n * H + c4];
            *(float4*)&As[r][64 + c4] = *(const float4*)&hroot[(size_t)n * H + c4];
        }
    }
    for (int i = t; i < 128 * 64; i += 256) {
        int k = i >> 6, j = i & 63;
        Ws[k][j] = (k < 64) ? Wr[k * 64 + j] : Wo[(k - 64) * 64 + j];
    }
    __syncthreads();
    int tr = t >> 4;                 // rows tr*2 .. +1
    int tc = t & 15;                 // cols tc*4 .. +3
    float acc[2][4];
    #pragma unroll
    for (int i = 0; i < 2; ++i)
        #pragma unroll
        for (int j = 0; j < 4; ++j) acc[i][j] = 0.f;
    #pragma unroll 2
    for (int k = 0; k < 128; k += 4) {
        float4 a0 = *(const float4*)&As[tr * 2][k];
        float4 a1 = *(const float4*)&As[tr * 2 + 1][k];
        #pragma unroll
        for (int kk = 0; kk < 4; ++kk) {
            float4 w = *(const float4*)&Ws[k + kk][tc * 4];
            float av0 = (kk == 0) ? a0.x : (kk == 1) ? a0.y : (kk == 2) ? a0.z : a0.w;
            float av1 = (kk == 0) ? a1.x : (kk == 1) ? a1.y : (kk == 2) ? a1.z : a1.w;
            acc[0][0] += av0 * w.x; acc[0][1] += av0 * w.y;
            acc[0][2] += av0 * w.z; acc[0][3] += av0 * w.w;
            acc[1][0] += av1 * w.x; acc[1][1] += av1 * w.y;
            acc[1][2] += av1 * w.z; acc[1][3] += av1 * w.w;
        }
    }
    int jb = tc * 4;
    float4 bj;
    bj.x = br[jb]     + bo[jb];
    bj.y = br[jb + 1] + bo[jb + 1];
    bj.z = br[jb + 2] + bo[jb + 2];
    bj.w = br[jb + 3] + bo[jb + 3];
    #pragma unroll
    for (int i = 0; i < 2; ++i) {
        int n = n0 + tr * 2 + i;
        if (n < N) {
            *(float4*)&xout[(size_t)n * H + jb] = make_float4(
                fmaxf(acc[i][0] + bj.x, 0.f), fmaxf(acc[i][1] + bj.y, 0.f),
                fmaxf(acc[i][2] + bj.z, 0.f), fmaxf(acc[i][3] + bj.w, 0.f));
        }
    }
}

// ---- pooled[batch[n]] += x[n], 16-node register pre-reduce (batch sorted) ----
__global__ __launch_bounds__(256) void k_pool(const float* __restrict__ x,
                                              const int* __restrict__ batch,
                                              float* __restrict__ pooled) {
    int c = threadIdx.x & 63;
    int grp = blockIdx.x * 4 + (threadIdx.x >> 6);
    int n0 = grp * 16;
    if (n0 >= N) return;
    int nend = min(n0 + 16, N);
    int curb = batch[n0];
    float acc = 0.f;
    for (int n = n0; n < nend; ++n) {
        int b = batch[n];
        if (b != curb) {
            atomicAdd(&pooled[curb * H + c], acc);
            acc = 0.f;
            curb = b;
        }
        acc += x[(size_t)n * H + c];
    }
    atomicAdd(&pooled[curb * H + c], acc);
}

// ---- out = relu(pooled @ finW1 + finb1) @ finW2 + finb2 ----
__global__ void k_final(const float* __restrict__ pooled,
                        const float* __restrict__ W1, const float* __restrict__ b1,
                        const float* __restrict__ W2, const float* __restrict__ b2,
                        float* __restrict__ out) {
    __shared__ float h[H];
    int g = blockIdx.x;
    int j = threadIdx.x;
    const float* p = pooled + (size_t)g * H;
    float acc = b1[j];
    #pragma unroll 8
    for (int k = 0; k < H; ++k) acc += p[k] * W1[k * H + j];
    h[j] = fmaxf(acc, 0.f);
    __syncthreads();
    if (j < OUTC) {
        float o = b2[j];
        #pragma unroll 8
        for (int k = 0; k < H; ++k) o += h[k] * W2[k * OUTC + j];
        out[(size_t)g * OUTC + j] = o;
    }
}

extern "C" void kernel_launch(void* const* d_in, const int* in_sizes, int n_in,
                              void* d_out, int out_size, void* d_ws, size_t ws_size,
                              hipStream_t stream) {
    const float* x         = (const float*)d_in[0];
    const float* edge_attr = (const float*)d_in[1];
    const float* P[16];
    for (int i = 0; i < 16; ++i) P[i] = (const float*)d_in[2 + i];
    const float* finW1 = (const float*)d_in[18];
    const float* finb1 = (const float*)d_in[19];
    const float* finW2 = (const float*)d_in[20];
    const float* finb2 = (const float*)d_in[21];
    const int* row   = (const int*)d_in[22];
    const int* col   = row + E;
    const int* batch = (const int*)d_in[23];
    float* out = (float*)d_out;
    (void)ws_size; (void)n_in; (void)in_sizes; (void)out_size;

    // ---- workspace ----
    float* fw = (float*)d_ws;
    float* zrel   = fw;  fw += (size_t)N * H;   // aliased by kvR during build
    float* hroot  = fw;  fw += (size_t)N * H;   // aliased by kvR during build
    float* x1     = fw;  fw += (size_t)N * H;   // aliased by kvC during build
    float* hrel   = fw;  fw += (size_t)N * H;   // aliased by kvC during build
    float* ea     = fw;  fw += (size_t)N * EC;
    float* pooled = fw;  fw += (size_t)G * H;
    int* iw = (int*)fw;
    int* cntR   = iw;  iw += NB;
    int* cntC   = iw;  iw += NB;
    int* baseR  = iw;  iw += NB;
    int* baseC  = iw;  iw += NB;
    int* curR   = iw;  iw += NB;
    int* curC   = iw;  iw += NB;
    int* offR   = iw;  iw += N + 1;
    int* offC   = iw;  iw += N + 1;
    int* eid    = iw;  iw += E;
    int* srcrow = iw;  iw += E;
    unsigned long long* kvR = (unsigned long long*)zrel;   // covers zrel+hroot
    unsigned long long* kvC = (unsigned long long*)x1;     // covers x1+hrel

    // ---- build CSR/CSC ----
    hipMemsetAsync(cntR, 0, 2 * (size_t)NB * sizeof(int), stream);
    hipMemsetAsync(pooled, 0, (size_t)G * H * sizeof(float), stream);
    int p1grid = (E + CHUNK - 1) / CHUNK;
    k_p1hist<<<p1grid, 256, 0, stream>>>(row, col, cntR, cntC);
    k_bscan<<<1, 256, 0, stream>>>(cntR, cntC, baseR, baseC, curR, curC, offR, offC);
    k_p1scat<<<p1grid, 256, 0, stream>>>(row, col, curR, curC, kvR, kvC);
    k_p2<<<2 * NB, 256, 0, stream>>>(kvR, kvC, baseR, baseC, cntR, cntC,
                                     offR, offC, eid, srcrow);

    // ---- shared edge aggregation ----
    k_ea_gather<<<(N + 3) / 4, 256, 0, stream>>>((const float4*)edge_attr, eid, offR,
                                                 (float4*)ea);

    int gmlp = (N + 31) / 32;   // 1563

    // ---- layer 1 ----
    k_mlp1g<<<gmlp, 256, 0, stream>>>(x, ea, P[0], P[4], P[5], zrel, hroot);
    k_gath<<<(N + 3) / 4, 256, 0, stream>>>((const float4*)zrel, srcrow, offC,
                                            (const float4*)P[1], (float4*)hrel);
    k_mlp2g<<<gmlp, 256, 0, stream>>>(hrel, hroot, P[2], P[6], P[3], P[7], x1);

    // ---- layer 2 ----
    k_mlp1g<<<gmlp, 256, 0, stream>>>(x1, ea, P[8], P[12], P[13], zrel, hroot);
    k_gath<<<(N + 3) / 4, 256, 0, stream>>>((const float4*)zrel, srcrow, offC,
                                            (const float4*)P[9], (float4*)hrel);
    k_mlp2g<<<gmlp, 256, 0, stream>>>(hrel, hroot, P[10], P[14], P[11], P[15], x1);

    // ---- pool + head ----
    k_pool<<<(N / 16 + 3) / 4, 256, 0, stream>>>(x1, batch, pooled);
    k_final<<<G, 64, 0, stream>>>(pooled, finW1, finb1, finW2, finb2, out);
}